// Round 14
// baseline (138.925 us; speedup 1.0000x reference)
//
#include <hip/hip_runtime.h>
#include <hip/hip_fp16.h>

// Problem constants (B,C,H,W = 2,3,96,96; D=32)
#define BB 2
#define CC 3
#define NN 9216   // 96*96
#define DD 32
#define NSPLIT 4                      // waves per block (key-quarters)
#define KEYS_PER_WAVE (NN / NSPLIT)   // 2304 (KSPLIT=1: whole key range in-block)
#define CHUNKS (KEYS_PER_WAVE / 64)   // 36
#define NGROUP (BB * NN / 32)         // 576 query groups = grid
#define L2E 1.44269504f
#define SZH ((size_t)BB * NN * DD)    // halves per prep buffer (589,824)

typedef _Float16 half8 __attribute__((ext_vector_type(8)));
typedef _Float16 half4v __attribute__((ext_vector_type(4)));
typedef __fp16 fp16x2 __attribute__((ext_vector_type(2)));
typedef float float4v __attribute__((ext_vector_type(4)));

#define MFMA_K32(a, b, c) __builtin_amdgcn_mfma_f32_16x16x32_f16((a), (b), (c), 0, 0, 0)

// ---------------------------------------------------------------------------
// Fused prep. Blocks [0,288): QK — thread per (b, n, part), hi/lo fp16 split,
// Q pre-scaled by log2(e). Weights staged in LDS (256 floats). Blocks
// [288,324): PROJECTED V — hP[c][n] plus a ONES row 3 (PV MFMA's row-3
// accumulator then computes the softmax denominator L for free).
// ---------------------------------------------------------------------------
__global__ __launch_bounds__(256) void prep_kernel(
    const float* __restrict__ img,
    const float* __restrict__ kw, const float* __restrict__ kb,
    const float* __restrict__ qw, const float* __restrict__ qb,
    const float* __restrict__ vw, const float* __restrict__ vb,
    const float* __restrict__ ow,
    _Float16* __restrict__ fH, _Float16* __restrict__ fL,
    _Float16* __restrict__ gH, _Float16* __restrict__ gL,
    _Float16* __restrict__ hP)
{
    __shared__ float wsm[256];   // kw[96] | qw[96] | kb[32] | qb[32]
    __shared__ float cwb[12];
    int bid = blockIdx.x;
    int t = threadIdx.x;
    if (bid < 288) {
        float v;
        if (t < 96)       v = kw[t];
        else if (t < 192) v = qw[t - 96];
        else if (t < 224) v = kb[t - 192];
        else              v = qb[t - 224];
        wsm[t] = v;
        __syncthreads();

        int id = bid * 256 + t;                    // [0, BB*NN*4)
        int part = id & 3;
        int n = (id >> 2) % NN;
        int b = (id >> 2) / NN;
        const float* xb = img + (size_t)b * CC * NN + n;
        float x0 = xb[0], x1 = xb[NN], x2 = xb[2 * NN];
        half8 fh, fl, gh, gl;
#pragma unroll
        for (int j = 0; j < 8; j++) {
            int d = part * 8 + j;
            float fv = wsm[d * 3 + 0] * x0 + wsm[d * 3 + 1] * x1 +
                       wsm[d * 3 + 2] * x2 + wsm[192 + d];
            float gv = (wsm[96 + d * 3 + 0] * x0 + wsm[96 + d * 3 + 1] * x1 +
                        wsm[96 + d * 3 + 2] * x2 + wsm[224 + d]) * L2E;
            _Float16 fhi = (_Float16)fv;
            _Float16 ghi = (_Float16)gv;
            fh[j] = fhi; fl[j] = (_Float16)(fv - (float)fhi);
            gh[j] = ghi; gl[j] = (_Float16)(gv - (float)ghi);
        }
        size_t off = ((size_t)b * NN + n) * DD + part * 8;
        *(half8*)(fH + off) = fh;
        *(half8*)(fL + off) = fl;
        *(half8*)(gH + off) = gh;
        *(half8*)(gL + off) = gl;
    } else {
        if (t < 9) {
            int c = t / 3, k = t % 3;
            float s = 0.f;
#pragma unroll
            for (int d = 0; d < DD; d++) s += ow[c * DD + d] * vw[d * 3 + k];
            cwb[t] = s;
        } else if (t < 12) {
            int c = t - 9;
            float s = 0.f;
#pragma unroll
            for (int d = 0; d < DD; d++) s += ow[c * DD + d] * vb[d];
            cwb[9 + c] = s;
        }
        __syncthreads();
        const int N8 = NN / 8;
        int id = (bid - 288) * 256 + t;            // [0, BB*4*N8) = 9216
        int n8 = id % N8;
        int row = (id / N8) & 3;
        int b = id / (N8 * 4);
        half8 hv = {1, 1, 1, 1, 1, 1, 1, 1};       // row 3: ONES (L computation)
        if (row < 3) {
            const float* xb = img + (size_t)b * CC * NN + n8 * 8;
            float w0 = cwb[row * 3 + 0], w1 = cwb[row * 3 + 1],
                  w2 = cwb[row * 3 + 2], bv = cwb[9 + row];
#pragma unroll
            for (int j = 0; j < 8; j++)
                hv[j] = (_Float16)(w0 * xb[j] + w1 * xb[NN + j] + w2 * xb[2 * NN + j] + bv);
        }
        *(half8*)(hP + ((size_t)(b * 4 + row)) * NN + n8 * 8) = hv;
    }
}

// ---------------------------------------------------------------------------
// Per-tile softmax + P staging (proven defer-max). Common path: per-lane
// balanced max (8 fmax, max3-fusable) + __any defer check (THR=8); the two
// dependent __shfl_xor run only in the rare rescale branch. No-trigger
// invariant: every lane's s <= mrun+8 -> P <= 2^8, fp16-safe; L/num
// accumulate in fp32 (2304 keys x 256 max = 590K, far below fp32 limits).
// First chunk always triggers (mrun = -1e30).
// ---------------------------------------------------------------------------
__device__ __forceinline__ void softmax_store(const float4v* s, float& mrun,
                                              float4v& acc, _Float16* Pw,
                                              int l16, int quad)
{
    float a0 = fmaxf(fmaxf(s[0][0], s[0][1]), s[0][2]);
    float a1 = fmaxf(fmaxf(s[0][3], s[1][0]), s[1][1]);
    float a2 = fmaxf(fmaxf(s[1][2], s[1][3]), s[2][0]);
    float a3 = fmaxf(fmaxf(s[2][1], s[2][2]), s[2][3]);
    float a4 = fmaxf(fmaxf(s[3][0], s[3][1]), s[3][2]);
    float lmax = fmaxf(fmaxf(fmaxf(a0, a1), fmaxf(a2, a3)), fmaxf(a4, s[3][3]));
    if (__any(lmax > mrun + 8.f)) {
        float mx = fmaxf(lmax, __shfl_xor(lmax, 16, 64));
        mx = fmaxf(mx, __shfl_xor(mx, 32, 64));
        float mnew = fmaxf(mrun, mx);
        float alpha = __builtin_amdgcn_exp2f(mrun - mnew);
#pragma unroll
        for (int r = 0; r < 4; r++) acc[r] *= alpha;   // incl. L row
        mrun = mnew;
    }
#pragma unroll
    for (int blk = 0; blk < 4; blk++) {
        float p0 = __builtin_amdgcn_exp2f(s[blk][0] - mrun);
        float p1 = __builtin_amdgcn_exp2f(s[blk][1] - mrun);
        float p2 = __builtin_amdgcn_exp2f(s[blk][2] - mrun);
        float p3 = __builtin_amdgcn_exp2f(s[blk][3] - mrun);
        union { fp16x2 h2[2]; half4v h4; } u;
        u.h2[0] = __builtin_amdgcn_cvt_pkrtz(p0, p1);
        u.h2[1] = __builtin_amdgcn_cvt_pkrtz(p2, p3);
        *(half4v*)(Pw + l16 * 72 + blk * 16 + quad * 4) = u.h4;
    }
}

// ---------------------------------------------------------------------------
// Flash attention, COMPLETE per block (KSPLIT=1): each block owns one
// 32-query group x ALL 9216 keys (4 waves x 2304 keys, 36 chunks). R13
// post-mortem: split-K x6 was a wash (fixed cost ate the util gain), and the
// 3-dispatch structure costs ~37 us for the merge dispatch + kernel-boundary
// L2 flush (R12 vs R13 A/B: 2-kernel non-attn = 28.5 us, 3-kernel = 65 us).
// With all partials in-block, the LSE merge + /L + bias + clamp + output
// write happen in the epilogue with plain __syncthreads — NO cross-block
// traffic, NO fences (R12's per-block __threadfence serialized the chip).
// Grid 576 < 1024 capacity: all blocks co-resident, single shot.
// Single-K-buffer refill pipeline (R9), QK0->sm0->QK1->sm1->PV order (R11),
// waves_per_eu(4,4) — the only proven no-spill operating point.
// L is produced by the PV MFMA's ones-row (acc reg 3).
// ---------------------------------------------------------------------------
__global__ __launch_bounds__(256)
__attribute__((amdgpu_waves_per_eu(4, 4)))
void attn_kernel(
    const _Float16* __restrict__ ws,
    const float* __restrict__ ob, float* __restrict__ out)
{
    const _Float16* fH = ws;                 // + 0*SZH (fL = +SZH)
    const _Float16* gH = ws + 2 * SZH;       // (gL = +SZH)
    const _Float16* hP = ws + 4 * SZH;

    const int g  = blockIdx.x;             // query group 0..575
    const int b = g / (NN / 32);
    const int m0 = (g % (NN / 32)) * 32;
    const int tid = threadIdx.x;
    const int w = tid >> 6;                // wave id 0..3 (key-quarter)
    const int lane = tid & 63;
    const int l16 = lane & 15;
    const int quad = lane >> 4;

    // Phase union: P staging (18432 B) / merge accumulators (rows c0..c2 + L)
    union SMem {
        _Float16 P[NSPLIT * 2 * 16 * 72];
        struct { float acc[NSPLIT][4][33]; float mbuf[NSPLIT][32]; } mg;
    };
    __shared__ __align__(16) SMem sm;

    // Q B-fragments for both tiles (hi + lo, log2e-scaled); gL = gH + SZH
    const _Float16* gHb = gH + ((size_t)b * NN + m0 + l16) * DD + quad * 8;
    half8 qh0 = *(const half8*)(gHb);
    half8 ql0 = *(const half8*)(gHb + SZH);
    half8 qh1 = *(const half8*)(gHb + (size_t)16 * DD);
    half8 ql1 = *(const half8*)(gHb + SZH + (size_t)16 * DD);

    float4v acc0 = {0,0,0,0};              // tile0: C[row][m=l16]; row3 = L
    float4v acc1 = {0,0,0,0};              // tile1
    float mrun0 = -1e30f;                  // per-lane col max (log2 domain)
    float mrun1 = -1e30f;

    const int nbase = w * KEYS_PER_WAVE;
    // hP^T A-frag pointer: row = min(l16,3) (rows 3..15 read the ONES row)
    const int vrow = (l16 < 3) ? l16 : 3;
    const _Float16* vp = hP + ((size_t)(b * 4 + vrow)) * NN + nbase + quad * 8;
    const _Float16* kp = fH + ((size_t)b * NN + nbase + l16) * DD + quad * 8;
    const _Float16* lp = kp + SZH;         // fL = fH + SZH
    _Float16* Pw0 = sm.P + (size_t)(w * 2 + 0) * 16 * 72;
    _Float16* Pw1 = sm.P + (size_t)(w * 2 + 1) * 16 * 72;

    // ---- prologue: chunk 0's K resident in the (single) K buffer
    half8 kC[4], lC[4];
#pragma unroll
    for (int blk = 0; blk < 4; blk++) {
        kC[blk] = *(const half8*)(kp + (size_t)(blk * 16) * DD);
        lC[blk] = *(const half8*)(lp + (size_t)(blk * 16) * DD);
    }
    kp += (size_t)64 * DD;                 // -> chunk 1
    lp += (size_t)64 * DD;

    for (int c = 0; c < CHUNKS; ++c) {
        float4v s[4];
        // ---- QK tile 0
#pragma unroll
        for (int blk = 0; blk < 4; blk++) {
            float4v z = {0,0,0,0};
            float4v t0 = MFMA_K32(kC[blk], ql0, z);
            t0 = MFMA_K32(lC[blk], qh0, t0);
            s[blk] = MFMA_K32(kC[blk], qh0, t0);
        }
        softmax_store(s, mrun0, acc0, Pw0, l16, quad);   // s dies here

        // ---- QK tile 1; each pair's refill issues right after its last read
        //      (WAR on kC/lC), covered by softmax1+PV (~200+ cyc). Final
        //      iteration over-reads <=1 KB into the adjacent buffer (unused).
#pragma unroll
        for (int blk = 0; blk < 4; blk++) {
            float4v z = {0,0,0,0};
            float4v t1 = MFMA_K32(kC[blk], ql1, z);
            t1 = MFMA_K32(lC[blk], qh1, t1);
            s[blk] = MFMA_K32(kC[blk], qh1, t1);
            kC[blk] = *(const half8*)(kp + (size_t)(blk * 16) * DD);
            lC[blk] = *(const half8*)(lp + (size_t)(blk * 16) * DD);
        }
        kp += (size_t)64 * DD;
        lp += (size_t)64 * DD;

        // V frags for THIS chunk: issued here, used after softmax1
        half8 vA0 = *(const half8*)(vp);
        half8 vA1 = *(const half8*)(vp + 32);

        softmax_store(s, mrun1, acc1, Pw1, l16, quad);

        // ---- PV: A = hP^T (3 rows + ONES pad), B = P (LDS b128)
        //      => C[row=c, col=m=l16], row 3 accumulates L
        {
            half8 pf0 = *(const half8*)(Pw0 + l16 * 72 + quad * 8);
            half8 pf1 = *(const half8*)(Pw0 + l16 * 72 + 32 + quad * 8);
            acc0 = MFMA_K32(vA0, pf0, acc0);
            acc0 = MFMA_K32(vA1, pf1, acc0);
            half8 qf0 = *(const half8*)(Pw1 + l16 * 72 + quad * 8);
            half8 qf1 = *(const half8*)(Pw1 + l16 * 72 + 32 + quad * 8);
            acc1 = MFMA_K32(vA0, qf0, acc1);
            acc1 = MFMA_K32(vA1, qf1, acc1);
        }
        vp += 64;
    }

    __syncthreads();   // all waves done with sm.P — safe to reuse as sm.mg

    // ---- write per-wave partials (fp32) for the in-block merge
    if (quad == 0) {
#pragma unroll
        for (int r = 0; r < 4; r++) {      // rows c=0..2 and L (r=3)
            sm.mg.acc[w][r][l16]      = acc0[r];
            sm.mg.acc[w][r][l16 + 16] = acc1[r];
        }
        sm.mg.mbuf[w][l16]      = mrun0;
        sm.mg.mbuf[w][l16 + 16] = mrun1;
    }
    __syncthreads();

    // ---- in-block LSE merge across the 4 key-quarter waves -> FINAL output
    if (tid < CC * 32) {
        int c = tid >> 5, m = tid & 31;
        float M = sm.mg.mbuf[0][m];
#pragma unroll
        for (int s2 = 1; s2 < NSPLIT; s2++) M = fmaxf(M, sm.mg.mbuf[s2][m]);
        float num = 0.f, L = 0.f;
#pragma unroll
        for (int s2 = 0; s2 < NSPLIT; s2++) {
            float e = __builtin_amdgcn_exp2f(sm.mg.mbuf[s2][m] - M);
            num += sm.mg.acc[s2][c][m] * e;
            L   += sm.mg.acc[s2][3][m] * e;
        }
        float o = num / L + ob[c];
        o = fminf(1.f, fmaxf(-1.f, o));
        out[((size_t)b * CC + c) * NN + m0 + m] = o;
    }
}

extern "C" void kernel_launch(void* const* d_in, const int* in_sizes, int n_in,
                              void* d_out, int out_size, void* d_ws, size_t ws_size,
                              hipStream_t stream) {
    const float* img = (const float*)d_in[0];
    const float* kw  = (const float*)d_in[1];
    const float* kb  = (const float*)d_in[2];
    const float* qw  = (const float*)d_in[3];
    const float* qb  = (const float*)d_in[4];
    const float* vw  = (const float*)d_in[5];
    const float* vb  = (const float*)d_in[6];
    const float* ow  = (const float*)d_in[7];
    const float* ob  = (const float*)d_in[8];
    float* out = (float*)d_out;

    // Workspace: fH,fL,gH,gL fp16 (4.7 MB) + hP fp16 [B][4][N] (148 KB).
    // No split-K partial buffers — the merge is fully in-block.
    _Float16* fH = (_Float16*)d_ws;
    _Float16* fL = fH + SZH;
    _Float16* gH = fL + SZH;
    _Float16* gL = gH + SZH;
    _Float16* hP = gL + SZH;

    prep_kernel<<<324, 256, 0, stream>>>(img, kw, kb, qw, qb, vw, vb, ow,
                                         fH, fL, gH, gL, hP);
    attn_kernel<<<NGROUP, 256, 0, stream>>>((const _Float16*)d_ws, ob, out);
}

// Round 15
// 114.026 us; speedup vs baseline: 1.2184x; 1.2184x over previous
//
#include <hip/hip_runtime.h>
#include <hip/hip_fp16.h>

// Problem constants (B,C,H,W = 2,3,96,96; D=32)
#define BB 2
#define CC 3
#define NN 9216   // 96*96
#define DD 32
#define NSPLIT 4                      // waves per block (key-quarters)
#define KSPLIT 2                      // blocks per 32-query group
#define KEYS_PER_WAVE (NN / (KSPLIT * NSPLIT))  // 1152
#define CHUNKS (KEYS_PER_WAVE / 64)   // 18
#define NGROUP (BB * NN / 32)         // 576 query groups
#define L2E 1.44269504f
#define SZH ((size_t)BB * NN * DD)    // halves per prep buffer (589,824)

typedef _Float16 half8 __attribute__((ext_vector_type(8)));
typedef _Float16 half4v __attribute__((ext_vector_type(4)));
typedef __fp16 fp16x2 __attribute__((ext_vector_type(2)));
typedef float float4v __attribute__((ext_vector_type(4)));

#define MFMA_K32(a, b, c) __builtin_amdgcn_mfma_f32_16x16x32_f16((a), (b), (c), 0, 0, 0)

// ---------------------------------------------------------------------------
// Fused prep. Blocks [0,288): K single-fp16 (fH) + Q hi/lo split (gH,gL),
// Q pre-scaled by log2(e). R15: fL dropped — the kl·q correction term's
// contribution is ~1.7e-3 rms in score units (K-rounding rms 3e-4 x sqrt(32))
// -> output absmax ~5e-3, well under the 2e-2 threshold. Halves K traffic
// and removes 8 MFMAs + 12 loads per chunk in attn. Weights staged in LDS.
// Blocks [288,324): PROJECTED V — hP[c][n] plus a ONES row 3 (PV MFMA's
// row-3 accumulator computes the softmax denominator L for free).
// ---------------------------------------------------------------------------
__global__ __launch_bounds__(256) void prep_kernel(
    const float* __restrict__ img,
    const float* __restrict__ kw, const float* __restrict__ kb,
    const float* __restrict__ qw, const float* __restrict__ qb,
    const float* __restrict__ vw, const float* __restrict__ vb,
    const float* __restrict__ ow,
    _Float16* __restrict__ fH,
    _Float16* __restrict__ gH, _Float16* __restrict__ gL,
    _Float16* __restrict__ hP)
{
    __shared__ float wsm[256];   // kw[96] | qw[96] | kb[32] | qb[32]
    __shared__ float cwb[12];
    int bid = blockIdx.x;
    int t = threadIdx.x;
    if (bid < 288) {
        float v;
        if (t < 96)       v = kw[t];
        else if (t < 192) v = qw[t - 96];
        else if (t < 224) v = kb[t - 192];
        else              v = qb[t - 224];
        wsm[t] = v;
        __syncthreads();

        int id = bid * 256 + t;                    // [0, BB*NN*4)
        int part = id & 3;
        int n = (id >> 2) % NN;
        int b = (id >> 2) / NN;
        const float* xb = img + (size_t)b * CC * NN + n;
        float x0 = xb[0], x1 = xb[NN], x2 = xb[2 * NN];
        half8 fh, gh, gl;
#pragma unroll
        for (int j = 0; j < 8; j++) {
            int d = part * 8 + j;
            float fv = wsm[d * 3 + 0] * x0 + wsm[d * 3 + 1] * x1 +
                       wsm[d * 3 + 2] * x2 + wsm[192 + d];
            float gv = (wsm[96 + d * 3 + 0] * x0 + wsm[96 + d * 3 + 1] * x1 +
                        wsm[96 + d * 3 + 2] * x2 + wsm[224 + d]) * L2E;
            _Float16 ghi = (_Float16)gv;
            fh[j] = (_Float16)fv;
            gh[j] = ghi; gl[j] = (_Float16)(gv - (float)ghi);
        }
        size_t off = ((size_t)b * NN + n) * DD + part * 8;
        *(half8*)(fH + off) = fh;
        *(half8*)(gH + off) = gh;
        *(half8*)(gL + off) = gl;
    } else {
        if (t < 9) {
            int c = t / 3, k = t % 3;
            float s = 0.f;
#pragma unroll
            for (int d = 0; d < DD; d++) s += ow[c * DD + d] * vw[d * 3 + k];
            cwb[t] = s;
        } else if (t < 12) {
            int c = t - 9;
            float s = 0.f;
#pragma unroll
            for (int d = 0; d < DD; d++) s += ow[c * DD + d] * vb[d];
            cwb[9 + c] = s;
        }
        __syncthreads();
        const int N8 = NN / 8;
        int id = (bid - 288) * 256 + t;            // [0, BB*4*N8) = 9216
        int n8 = id % N8;
        int row = (id / N8) & 3;
        int b = id / (N8 * 4);
        half8 hv = {1, 1, 1, 1, 1, 1, 1, 1};       // row 3: ONES (L computation)
        if (row < 3) {
            const float* xb = img + (size_t)b * CC * NN + n8 * 8;
            float w0 = cwb[row * 3 + 0], w1 = cwb[row * 3 + 1],
                  w2 = cwb[row * 3 + 2], bv = cwb[9 + row];
#pragma unroll
            for (int j = 0; j < 8; j++)
                hv[j] = (_Float16)(w0 * xb[j] + w1 * xb[NN + j] + w2 * xb[2 * NN + j] + bv);
        }
        *(half8*)(hP + ((size_t)(b * 4 + row)) * NN + n8 * 8) = hv;
    }
}

// ---------------------------------------------------------------------------
// Per-tile softmax + P staging (proven defer-max). Common path: per-lane
// balanced max (8 fmax, max3-fusable) + __any defer check (THR=8); the two
// dependent __shfl_xor run only in the rare rescale branch. No-trigger
// invariant: every lane's s <= mrun+8 -> P <= 2^8, fp16-safe; L/num
// accumulate in fp32. First chunk always triggers (mrun = -1e30).
// ---------------------------------------------------------------------------
__device__ __forceinline__ void softmax_store(const float4v* s, float& mrun,
                                              float4v& acc, _Float16* Pw,
                                              int l16, int quad)
{
    float a0 = fmaxf(fmaxf(s[0][0], s[0][1]), s[0][2]);
    float a1 = fmaxf(fmaxf(s[0][3], s[1][0]), s[1][1]);
    float a2 = fmaxf(fmaxf(s[1][2], s[1][3]), s[2][0]);
    float a3 = fmaxf(fmaxf(s[2][1], s[2][2]), s[2][3]);
    float a4 = fmaxf(fmaxf(s[3][0], s[3][1]), s[3][2]);
    float lmax = fmaxf(fmaxf(fmaxf(a0, a1), fmaxf(a2, a3)), fmaxf(a4, s[3][3]));
    if (__any(lmax > mrun + 8.f)) {
        float mx = fmaxf(lmax, __shfl_xor(lmax, 16, 64));
        mx = fmaxf(mx, __shfl_xor(mx, 32, 64));
        float mnew = fmaxf(mrun, mx);
        float alpha = __builtin_amdgcn_exp2f(mrun - mnew);
#pragma unroll
        for (int r = 0; r < 4; r++) acc[r] *= alpha;   // incl. L row
        mrun = mnew;
    }
#pragma unroll
    for (int blk = 0; blk < 4; blk++) {
        float p0 = __builtin_amdgcn_exp2f(s[blk][0] - mrun);
        float p1 = __builtin_amdgcn_exp2f(s[blk][1] - mrun);
        float p2 = __builtin_amdgcn_exp2f(s[blk][2] - mrun);
        float p3 = __builtin_amdgcn_exp2f(s[blk][3] - mrun);
        union { fp16x2 h2[2]; half4v h4; } u;
        u.h2[0] = __builtin_amdgcn_cvt_pkrtz(p0, p1);
        u.h2[1] = __builtin_amdgcn_cvt_pkrtz(p2, p3);
        *(half4v*)(Pw + l16 * 72 + blk * 16 + quad * 4) = u.h4;
    }
}

// ---------------------------------------------------------------------------
// Flash attention PARTIAL, cross-block split-K x2, 4 waves/block, 2 Q-tiles
// per wave. R15: K is single-fp16 (fL dropped) -> QK = 2 MFMAs per 16-key
// blk (K x Q_lo + K x Q_hi), K refill = 4 loads/chunk (was 16). Natural
// live set ~45-50 regs -> waves_per_eu(6,6) (budget 85): 6 blocks/CU,
// capacity 1536 >= grid 1152 -> ONE dispatch round at 75% fill (R9's
// two-round 56% was the top quantified loss). R14 A/B proved the merge
// dispatch is free (non-attn constant ~64.5 us either way) — keep 3-kernel.
// Single-K-buffer refill pipeline (R9), QK0->sm0->QK1->sm1->PV (R11).
// L is produced by the PV MFMA's ones-row (acc reg 3).
// ---------------------------------------------------------------------------
__global__ __launch_bounds__(256)
__attribute__((amdgpu_waves_per_eu(6, 6)))
void attn_partial_kernel(
    const _Float16* __restrict__ ws,
    float* __restrict__ pnum, float* __restrict__ pM)
{
    const _Float16* fH = ws;                 // K hi (single precision)
    const _Float16* gH = ws + SZH;           // Q hi (gL = +SZH)
    const _Float16* hP = ws + 3 * SZH;

    const int gb = blockIdx.x;             // 0 .. NGROUP*KSPLIT-1
    const int g  = gb / KSPLIT;            // query group
    const int ks = gb % KSPLIT;            // key-split id
    const int b = g / (NN / 32);
    const int m0 = (g % (NN / 32)) * 32;
    const int tid = threadIdx.x;
    const int w = tid >> 6;                // wave id 0..3 (key-quarter)
    const int lane = tid & 63;
    const int l16 = lane & 15;
    const int quad = lane >> 4;

    // Phase union: P staging (18432 B) / merge accumulators (rows c0..c2 + L)
    union SMem {
        _Float16 P[NSPLIT * 2 * 16 * 72];
        struct { float acc[NSPLIT][4][33]; float mbuf[NSPLIT][32]; } mg;
    };
    __shared__ __align__(16) SMem sm;

    // Q B-fragments for both tiles (hi + lo, log2e-scaled); gL = gH + SZH
    const _Float16* gHb = gH + ((size_t)b * NN + m0 + l16) * DD + quad * 8;
    half8 qh0 = *(const half8*)(gHb);
    half8 ql0 = *(const half8*)(gHb + SZH);
    half8 qh1 = *(const half8*)(gHb + (size_t)16 * DD);
    half8 ql1 = *(const half8*)(gHb + SZH + (size_t)16 * DD);

    float4v acc0 = {0,0,0,0};              // tile0: C[row][m=l16]; row3 = L
    float4v acc1 = {0,0,0,0};              // tile1
    float mrun0 = -1e30f;                  // per-lane col max (log2 domain)
    float mrun1 = -1e30f;

    const int nbase = ks * (NN / KSPLIT) + w * KEYS_PER_WAVE;
    // hP^T A-frag pointer: row = min(l16,3) (rows 3..15 read the ONES row)
    const int vrow = (l16 < 3) ? l16 : 3;
    const _Float16* vp = hP + ((size_t)(b * 4 + vrow)) * NN + nbase + quad * 8;
    const _Float16* kp = fH + ((size_t)b * NN + nbase + l16) * DD + quad * 8;
    _Float16* Pw0 = sm.P + (size_t)(w * 2 + 0) * 16 * 72;
    _Float16* Pw1 = sm.P + (size_t)(w * 2 + 1) * 16 * 72;

    // ---- prologue: chunk 0's K resident in the (single) K buffer
    half8 kC[4];
#pragma unroll
    for (int blk = 0; blk < 4; blk++)
        kC[blk] = *(const half8*)(kp + (size_t)(blk * 16) * DD);
    kp += (size_t)64 * DD;                 // -> chunk 1

    for (int c = 0; c < CHUNKS; ++c) {
        float4v s[4];
        // ---- QK tile 0: s = K x (Q_lo + Q_hi), single-precision K
#pragma unroll
        for (int blk = 0; blk < 4; blk++) {
            float4v z = {0,0,0,0};
            float4v t0 = MFMA_K32(kC[blk], ql0, z);
            s[blk] = MFMA_K32(kC[blk], qh0, t0);
        }
        softmax_store(s, mrun0, acc0, Pw0, l16, quad);   // s dies here

        // ---- QK tile 1; refill kC[blk] right after its last read (WAR),
        //      covered by softmax1+PV (~200+ cyc). Final iteration
        //      over-reads <=1 KB into the adjacent buffer (unused).
#pragma unroll
        for (int blk = 0; blk < 4; blk++) {
            float4v z = {0,0,0,0};
            float4v t1 = MFMA_K32(kC[blk], ql1, z);
            s[blk] = MFMA_K32(kC[blk], qh1, t1);
            kC[blk] = *(const half8*)(kp + (size_t)(blk * 16) * DD);
        }
        kp += (size_t)64 * DD;

        // V frags for THIS chunk: issued here, used after softmax1
        half8 vA0 = *(const half8*)(vp);
        half8 vA1 = *(const half8*)(vp + 32);

        softmax_store(s, mrun1, acc1, Pw1, l16, quad);

        // ---- PV: A = hP^T (3 rows + ONES pad), B = P (LDS b128)
        //      => C[row=c, col=m=l16], row 3 accumulates L
        {
            half8 pf0 = *(const half8*)(Pw0 + l16 * 72 + quad * 8);
            half8 pf1 = *(const half8*)(Pw0 + l16 * 72 + 32 + quad * 8);
            acc0 = MFMA_K32(vA0, pf0, acc0);
            acc0 = MFMA_K32(vA1, pf1, acc0);
            half8 qf0 = *(const half8*)(Pw1 + l16 * 72 + quad * 8);
            half8 qf1 = *(const half8*)(Pw1 + l16 * 72 + 32 + quad * 8);
            acc1 = MFMA_K32(vA0, qf0, acc1);
            acc1 = MFMA_K32(vA1, qf1, acc1);
        }
        vp += 64;
    }

    __syncthreads();   // all waves done with sm.P — safe to reuse as sm.mg

    // ---- write per-wave partials (fp32) for the in-block merge
    if (quad == 0) {
#pragma unroll
        for (int r = 0; r < 4; r++) {      // rows c=0..2 and L (r=3)
            sm.mg.acc[w][r][l16]      = acc0[r];
            sm.mg.acc[w][r][l16 + 16] = acc1[r];
        }
        sm.mg.mbuf[w][l16]      = mrun0;
        sm.mg.mbuf[w][l16 + 16] = mrun1;
    }
    __syncthreads();

    // ---- merge NSPLIT waves -> un-normalized block partial -> global
    if (tid < 4 * 32) {
        int c = tid >> 5, m = tid & 31;    // c=3 row is L
        float M = sm.mg.mbuf[0][m];
#pragma unroll
        for (int s2 = 1; s2 < NSPLIT; s2++) M = fmaxf(M, sm.mg.mbuf[s2][m]);
        float v = 0.f;
#pragma unroll
        for (int s2 = 0; s2 < NSPLIT; s2++)
            v += sm.mg.acc[s2][c][m] * __builtin_amdgcn_exp2f(sm.mg.mbuf[s2][m] - M);
        pnum[(size_t)gb * 128 + tid] = v;
        if (c == 0) pM[gb * 32 + m] = M;
    }
}

// ---------------------------------------------------------------------------
// Final merge: KSPLIT-way log-sum-exp combine of the block partials, + ob,
// clamp. L lives in pnum row 3 (from the MFMA ones-row).
// ---------------------------------------------------------------------------
__global__ __launch_bounds__(128) void merge_kernel(
    const float* __restrict__ pnum, const float* __restrict__ pM,
    const float* __restrict__ ob, float* __restrict__ out)
{
    const int g = blockIdx.x;              // 0 .. NGROUP-1
    const int b = g / (NN / 32);
    const int m0 = (g % (NN / 32)) * 32;
    const int tid = threadIdx.x;

    if (tid < CC * 32) {
        int c = tid >> 5, m = tid & 31;
        int base = g * KSPLIT;
        float M = pM[base * 32 + m];
#pragma unroll
        for (int k = 1; k < KSPLIT; k++) M = fmaxf(M, pM[(base + k) * 32 + m]);
        float num = 0.f, L = 0.f;
#pragma unroll
        for (int k = 0; k < KSPLIT; k++) {
            float e = __builtin_amdgcn_exp2f(pM[(base + k) * 32 + m] - M);
            num += pnum[(size_t)(base + k) * 128 + c * 32 + m] * e;
            L   += pnum[(size_t)(base + k) * 128 + 96 + m] * e;
        }
        float o = num / L + ob[c];
        o = fminf(1.f, fmaxf(-1.f, o));
        out[((size_t)b * CC + c) * NN + m0 + m] = o;
    }
}

extern "C" void kernel_launch(void* const* d_in, const int* in_sizes, int n_in,
                              void* d_out, int out_size, void* d_ws, size_t ws_size,
                              hipStream_t stream) {
    const float* img = (const float*)d_in[0];
    const float* kw  = (const float*)d_in[1];
    const float* kb  = (const float*)d_in[2];
    const float* qw  = (const float*)d_in[3];
    const float* qb  = (const float*)d_in[4];
    const float* vw  = (const float*)d_in[5];
    const float* vb  = (const float*)d_in[6];
    const float* ow  = (const float*)d_in[7];
    const float* ob  = (const float*)d_in[8];
    float* out = (float*)d_out;

    // Workspace: fH,gH,gL fp16 (3.5 MB) + hP fp16 [B][4][N] (148 KB)
    // + pnum (590 KB) + pM (147 KB) ~= 4.4 MB
    _Float16* fH = (_Float16*)d_ws;
    _Float16* gH = fH + SZH;
    _Float16* gL = gH + SZH;
    _Float16* hP = gL + SZH;
    float* pnum = (float*)(hP + (size_t)BB * 4 * NN);
    float* pM   = pnum + (size_t)NGROUP * KSPLIT * 128;

    prep_kernel<<<324, 256, 0, stream>>>(img, kw, kb, qw, qb, vw, vb, ow,
                                         fH, gH, gL, hP);
    attn_partial_kernel<<<NGROUP * KSPLIT, 256, 0, stream>>>(
        (const _Float16*)d_ws, pnum, pM);
    merge_kernel<<<NGROUP, 128, 0, stream>>>(pnum, pM, ob, out);
}

// Round 16
// 111.868 us; speedup vs baseline: 1.2419x; 1.0193x over previous
//
#include <hip/hip_runtime.h>
#include <hip/hip_fp16.h>

// Problem constants (B,C,H,W = 2,3,96,96; D=32)
#define BB 2
#define CC 3
#define NN 9216   // 96*96
#define DD 32
#define NSPLIT 4                      // waves per block (key-quarters)
#define KSPLIT 2                      // blocks per 32-query group
#define KEYS_PER_WAVE (NN / (KSPLIT * NSPLIT))  // 1152
#define CHUNKS (KEYS_PER_WAVE / 64)   // 18
#define NGROUP (BB * NN / 32)         // 576 query groups
#define L2E 1.44269504f
#define SZH ((size_t)BB * NN * DD)    // halves per prep buffer (589,824)

typedef _Float16 half8 __attribute__((ext_vector_type(8)));
typedef _Float16 half4v __attribute__((ext_vector_type(4)));
typedef __fp16 fp16x2 __attribute__((ext_vector_type(2)));
typedef float float4v __attribute__((ext_vector_type(4)));

#define MFMA_K32(a, b, c) __builtin_amdgcn_mfma_f32_16x16x32_f16((a), (b), (c), 0, 0, 0)

// ---------------------------------------------------------------------------
// Fused prep. Blocks [0,288): K single-fp16 (fH) + Q hi/lo split (gH,gL),
// Q pre-scaled by log2(e) (R15: fL dropped, absmax margin verified 0.0156 <
// 0.02). Weights staged in LDS. Blocks [288,324): PROJECTED V — hP[c][n]
// plus a ONES row 3 (PV MFMA's row-3 accumulator computes the softmax
// denominator L for free).
// ---------------------------------------------------------------------------
__global__ __launch_bounds__(256) void prep_kernel(
    const float* __restrict__ img,
    const float* __restrict__ kw, const float* __restrict__ kb,
    const float* __restrict__ qw, const float* __restrict__ qb,
    const float* __restrict__ vw, const float* __restrict__ vb,
    const float* __restrict__ ow,
    _Float16* __restrict__ fH,
    _Float16* __restrict__ gH, _Float16* __restrict__ gL,
    _Float16* __restrict__ hP)
{
    __shared__ float wsm[256];   // kw[96] | qw[96] | kb[32] | qb[32]
    __shared__ float cwb[12];
    int bid = blockIdx.x;
    int t = threadIdx.x;
    if (bid < 288) {
        float v;
        if (t < 96)       v = kw[t];
        else if (t < 192) v = qw[t - 96];
        else if (t < 224) v = kb[t - 192];
        else              v = qb[t - 224];
        wsm[t] = v;
        __syncthreads();

        int id = bid * 256 + t;                    // [0, BB*NN*4)
        int part = id & 3;
        int n = (id >> 2) % NN;
        int b = (id >> 2) / NN;
        const float* xb = img + (size_t)b * CC * NN + n;
        float x0 = xb[0], x1 = xb[NN], x2 = xb[2 * NN];
        half8 fh, gh, gl;
#pragma unroll
        for (int j = 0; j < 8; j++) {
            int d = part * 8 + j;
            float fv = wsm[d * 3 + 0] * x0 + wsm[d * 3 + 1] * x1 +
                       wsm[d * 3 + 2] * x2 + wsm[192 + d];
            float gv = (wsm[96 + d * 3 + 0] * x0 + wsm[96 + d * 3 + 1] * x1 +
                        wsm[96 + d * 3 + 2] * x2 + wsm[224 + d]) * L2E;
            _Float16 ghi = (_Float16)gv;
            fh[j] = (_Float16)fv;
            gh[j] = ghi; gl[j] = (_Float16)(gv - (float)ghi);
        }
        size_t off = ((size_t)b * NN + n) * DD + part * 8;
        *(half8*)(fH + off) = fh;
        *(half8*)(gH + off) = gh;
        *(half8*)(gL + off) = gl;
    } else {
        if (t < 9) {
            int c = t / 3, k = t % 3;
            float s = 0.f;
#pragma unroll
            for (int d = 0; d < DD; d++) s += ow[c * DD + d] * vw[d * 3 + k];
            cwb[t] = s;
        } else if (t < 12) {
            int c = t - 9;
            float s = 0.f;
#pragma unroll
            for (int d = 0; d < DD; d++) s += ow[c * DD + d] * vb[d];
            cwb[9 + c] = s;
        }
        __syncthreads();
        const int N8 = NN / 8;
        int id = (bid - 288) * 256 + t;            // [0, BB*4*N8) = 9216
        int n8 = id % N8;
        int row = (id / N8) & 3;
        int b = id / (N8 * 4);
        half8 hv = {1, 1, 1, 1, 1, 1, 1, 1};       // row 3: ONES (L computation)
        if (row < 3) {
            const float* xb = img + (size_t)b * CC * NN + n8 * 8;
            float w0 = cwb[row * 3 + 0], w1 = cwb[row * 3 + 1],
                  w2 = cwb[row * 3 + 2], bv = cwb[9 + row];
#pragma unroll
            for (int j = 0; j < 8; j++)
                hv[j] = (_Float16)(w0 * xb[j] + w1 * xb[NN + j] + w2 * xb[2 * NN + j] + bv);
        }
        *(half8*)(hP + ((size_t)(b * 4 + row)) * NN + n8 * 8) = hv;
    }
}

// ---------------------------------------------------------------------------
// Per-tile softmax + P staging. R16: scores arrive RELATIVE (the QK MFMA's
// C-operand was initialized to -mrun, legal because all 4 acc regs of a lane
// belong to the same query column m=l16 and mrun is per-column) — so the
// common path is P = exp2(s) with NO subtracts, and the defer check is a
// compare against the constant THR=8. The trigger branch (rare) does the
// cross-lane max, rescales acc, subtracts delta from s in place, and bumps
// mrun. mrun starts at 0 (NOT -1e30: a huge C-init would destroy score
// precision in the fp32 accumulate): columns whose max stays < 8 simply
// never rescale — P <= 2^8, exactly the defer-max fp16-safe invariant.
// ---------------------------------------------------------------------------
__device__ __forceinline__ void softmax_store(float4v (&s)[4], float& mrun,
                                              float4v& acc, _Float16* Pw,
                                              int l16, int quad)
{
    float a0 = fmaxf(fmaxf(s[0][0], s[0][1]), s[0][2]);
    float a1 = fmaxf(fmaxf(s[0][3], s[1][0]), s[1][1]);
    float a2 = fmaxf(fmaxf(s[1][2], s[1][3]), s[2][0]);
    float a3 = fmaxf(fmaxf(s[2][1], s[2][2]), s[2][3]);
    float a4 = fmaxf(fmaxf(s[3][0], s[3][1]), s[3][2]);
    float lmax = fmaxf(fmaxf(fmaxf(a0, a1), fmaxf(a2, a3)), fmaxf(a4, s[3][3]));
    if (__any(lmax > 8.f)) {
        float mx = fmaxf(lmax, __shfl_xor(lmax, 16, 64));
        mx = fmaxf(mx, __shfl_xor(mx, 32, 64));     // per-column max (quads)
        float d = fmaxf(mx, 0.f);                   // monotone running max
        float alpha = __builtin_amdgcn_exp2f(-d);
#pragma unroll
        for (int r = 0; r < 4; r++) acc[r] *= alpha;   // incl. L row
        mrun += d;
#pragma unroll
        for (int blk = 0; blk < 4; blk++)
#pragma unroll
            for (int j = 0; j < 4; j++) s[blk][j] -= d;   // trigger-only subs
    }
#pragma unroll
    for (int blk = 0; blk < 4; blk++) {
        float p0 = __builtin_amdgcn_exp2f(s[blk][0]);
        float p1 = __builtin_amdgcn_exp2f(s[blk][1]);
        float p2 = __builtin_amdgcn_exp2f(s[blk][2]);
        float p3 = __builtin_amdgcn_exp2f(s[blk][3]);
        union { fp16x2 h2[2]; half4v h4; } u;
        u.h2[0] = __builtin_amdgcn_cvt_pkrtz(p0, p1);
        u.h2[1] = __builtin_amdgcn_cvt_pkrtz(p2, p3);
        *(half4v*)(Pw + l16 * 72 + blk * 16 + quad * 4) = u.h4;
    }
}

// ---------------------------------------------------------------------------
// Flash attention PARTIAL, cross-block split-K x2, 4 waves/block, 2 Q-tiles
// per wave. R15 structure (K single-fp16, 2 MFMAs/16-key blk, 4 K loads per
// chunk, waves_per_eu(6,6) proven no-spill at VGPR 40). R16 delta: -mrun is
// folded into the QK MFMA C-init (zm0/zm1), deleting the 32 per-chunk
// common-path subtracts; V loads hoisted before sm0 (~400 cyc cover for PV).
// Single-K-buffer refill pipeline (R9), QK0->sm0->QK1->sm1->PV (R11).
// L is produced by the PV MFMA's ones-row (acc reg 3).
// ---------------------------------------------------------------------------
__global__ __launch_bounds__(256)
__attribute__((amdgpu_waves_per_eu(6, 6)))
void attn_partial_kernel(
    const _Float16* __restrict__ ws,
    float* __restrict__ pnum, float* __restrict__ pM)
{
    const _Float16* fH = ws;                 // K hi (single precision)
    const _Float16* gH = ws + SZH;           // Q hi (gL = +SZH)
    const _Float16* hP = ws + 3 * SZH;

    const int gb = blockIdx.x;             // 0 .. NGROUP*KSPLIT-1
    const int g  = gb / KSPLIT;            // query group
    const int ks = gb % KSPLIT;            // key-split id
    const int b = g / (NN / 32);
    const int m0 = (g % (NN / 32)) * 32;
    const int tid = threadIdx.x;
    const int w = tid >> 6;                // wave id 0..3 (key-quarter)
    const int lane = tid & 63;
    const int l16 = lane & 15;
    const int quad = lane >> 4;

    // Phase union: P staging (18432 B) / merge accumulators (rows c0..c2 + L)
    union SMem {
        _Float16 P[NSPLIT * 2 * 16 * 72];
        struct { float acc[NSPLIT][4][33]; float mbuf[NSPLIT][32]; } mg;
    };
    __shared__ __align__(16) SMem sm;

    // Q B-fragments for both tiles (hi + lo, log2e-scaled); gL = gH + SZH
    const _Float16* gHb = gH + ((size_t)b * NN + m0 + l16) * DD + quad * 8;
    half8 qh0 = *(const half8*)(gHb);
    half8 ql0 = *(const half8*)(gHb + SZH);
    half8 qh1 = *(const half8*)(gHb + (size_t)16 * DD);
    half8 ql1 = *(const half8*)(gHb + SZH + (size_t)16 * DD);

    float4v acc0 = {0,0,0,0};              // tile0: C[row][m=l16]; row3 = L
    float4v acc1 = {0,0,0,0};              // tile1
    float mrun0 = 0.f;                     // per-COLUMN running max, rel. 0
    float mrun1 = 0.f;

    const int nbase = ks * (NN / KSPLIT) + w * KEYS_PER_WAVE;
    // hP^T A-frag pointer: row = min(l16,3) (rows 3..15 read the ONES row)
    const int vrow = (l16 < 3) ? l16 : 3;
    const _Float16* vp = hP + ((size_t)(b * 4 + vrow)) * NN + nbase + quad * 8;
    const _Float16* kp = fH + ((size_t)b * NN + nbase + l16) * DD + quad * 8;
    _Float16* Pw0 = sm.P + (size_t)(w * 2 + 0) * 16 * 72;
    _Float16* Pw1 = sm.P + (size_t)(w * 2 + 1) * 16 * 72;

    // ---- prologue: chunk 0's K resident in the (single) K buffer
    half8 kC[4];
#pragma unroll
    for (int blk = 0; blk < 4; blk++)
        kC[blk] = *(const half8*)(kp + (size_t)(blk * 16) * DD);
    kp += (size_t)64 * DD;                 // -> chunk 1

    for (int c = 0; c < CHUNKS; ++c) {
        float4v s[4];
        // ---- QK tile 0: C-init = -mrun0 folds the softmax shift for free
        {
            float4v zm0 = {-mrun0, -mrun0, -mrun0, -mrun0};
#pragma unroll
            for (int blk = 0; blk < 4; blk++) {
                float4v t0 = MFMA_K32(kC[blk], ql0, zm0);
                s[blk] = MFMA_K32(kC[blk], qh0, t0);
            }
        }
        softmax_store(s, mrun0, acc0, Pw0, l16, quad);   // s dies here

        // ---- QK tile 1 (C-init = -mrun1); refill kC[blk] right after its
        //      last read (WAR), covered by sm1+PV (~300 cyc). Final iteration
        //      over-reads <=1 KB into the adjacent buffer (unused).
        {
            float4v zm1 = {-mrun1, -mrun1, -mrun1, -mrun1};
#pragma unroll
            for (int blk = 0; blk < 4; blk++) {
                float4v t1 = MFMA_K32(kC[blk], ql1, zm1);
                s[blk] = MFMA_K32(kC[blk], qh1, t1);
                kC[blk] = *(const half8*)(kp + (size_t)(blk * 16) * DD);
            }
        }
        kp += (size_t)64 * DD;

        // V frags for THIS chunk: issued here, used in PV (~400 cyc cover)
        half8 vA0 = *(const half8*)(vp);
        half8 vA1 = *(const half8*)(vp + 32);

        softmax_store(s, mrun1, acc1, Pw1, l16, quad);

        // ---- PV: A = hP^T (3 rows + ONES pad), B = P (LDS b128)
        //      => C[row=c, col=m=l16], row 3 accumulates L
        {
            half8 pf0 = *(const half8*)(Pw0 + l16 * 72 + quad * 8);
            half8 pf1 = *(const half8*)(Pw0 + l16 * 72 + 32 + quad * 8);
            acc0 = MFMA_K32(vA0, pf0, acc0);
            acc0 = MFMA_K32(vA1, pf1, acc0);
            half8 qf0 = *(const half8*)(Pw1 + l16 * 72 + quad * 8);
            half8 qf1 = *(const half8*)(Pw1 + l16 * 72 + 32 + quad * 8);
            acc1 = MFMA_K32(vA0, qf0, acc1);
            acc1 = MFMA_K32(vA1, qf1, acc1);
        }
        vp += 64;
    }

    __syncthreads();   // all waves done with sm.P — safe to reuse as sm.mg

    // ---- write per-wave partials (fp32) for the in-block merge
    if (quad == 0) {
#pragma unroll
        for (int r = 0; r < 4; r++) {      // rows c=0..2 and L (r=3)
            sm.mg.acc[w][r][l16]      = acc0[r];
            sm.mg.acc[w][r][l16 + 16] = acc1[r];
        }
        sm.mg.mbuf[w][l16]      = mrun0;
        sm.mg.mbuf[w][l16 + 16] = mrun1;
    }
    __syncthreads();

    // ---- merge NSPLIT waves -> un-normalized block partial -> global
    if (tid < 4 * 32) {
        int c = tid >> 5, m = tid & 31;    // c=3 row is L
        float M = sm.mg.mbuf[0][m];
#pragma unroll
        for (int s2 = 1; s2 < NSPLIT; s2++) M = fmaxf(M, sm.mg.mbuf[s2][m]);
        float v = 0.f;
#pragma unroll
        for (int s2 = 0; s2 < NSPLIT; s2++)
            v += sm.mg.acc[s2][c][m] * __builtin_amdgcn_exp2f(sm.mg.mbuf[s2][m] - M);
        pnum[(size_t)gb * 128 + tid] = v;
        if (c == 0) pM[gb * 32 + m] = M;
    }
}

// ---------------------------------------------------------------------------
// Final merge: KSPLIT-way log-sum-exp combine of the block partials, + ob,
// clamp. L lives in pnum row 3 (from the MFMA ones-row).
// ---------------------------------------------------------------------------
__global__ __launch_bounds__(128) void merge_kernel(
    const float* __restrict__ pnum, const float* __restrict__ pM,
    const float* __restrict__ ob, float* __restrict__ out)
{
    const int g = blockIdx.x;              // 0 .. NGROUP-1
    const int b = g / (NN / 32);
    const int m0 = (g % (NN / 32)) * 32;
    const int tid = threadIdx.x;

    if (tid < CC * 32) {
        int c = tid >> 5, m = tid & 31;
        int base = g * KSPLIT;
        float M = pM[base * 32 + m];
#pragma unroll
        for (int k = 1; k < KSPLIT; k++) M = fmaxf(M, pM[(base + k) * 32 + m]);
        float num = 0.f, L = 0.f;
#pragma unroll
        for (int k = 0; k < KSPLIT; k++) {
            float e = __builtin_amdgcn_exp2f(pM[(base + k) * 32 + m] - M);
            num += pnum[(size_t)(base + k) * 128 + c * 32 + m] * e;
            L   += pnum[(size_t)(base + k) * 128 + 96 + m] * e;
        }
        float o = num / L + ob[c];
        o = fminf(1.f, fmaxf(-1.f, o));
        out[((size_t)b * CC + c) * NN + m0 + m] = o;
    }
}

extern "C" void kernel_launch(void* const* d_in, const int* in_sizes, int n_in,
                              void* d_out, int out_size, void* d_ws, size_t ws_size,
                              hipStream_t stream) {
    const float* img = (const float*)d_in[0];
    const float* kw  = (const float*)d_in[1];
    const float* kb  = (const float*)d_in[2];
    const float* qw  = (const float*)d_in[3];
    const float* qb  = (const float*)d_in[4];
    const float* vw  = (const float*)d_in[5];
    const float* vb  = (const float*)d_in[6];
    const float* ow  = (const float*)d_in[7];
    const float* ob  = (const float*)d_in[8];
    float* out = (float*)d_out;

    // Workspace: fH,gH,gL fp16 (3.5 MB) + hP fp16 [B][4][N] (148 KB)
    // + pnum (590 KB) + pM (147 KB) ~= 4.4 MB
    _Float16* fH = (_Float16*)d_ws;
    _Float16* gH = fH + SZH;
    _Float16* gL = gH + SZH;
    _Float16* hP = gL + SZH;
    float* pnum = (float*)(hP + (size_t)BB * 4 * NN);
    float* pM   = pnum + (size_t)NGROUP * KSPLIT * 128;

    prep_kernel<<<324, 256, 0, stream>>>(img, kw, kb, qw, qb, vw, vb, ow,
                                         fH, gH, gL, hP);
    attn_partial_kernel<<<NGROUP * KSPLIT, 256, 0, stream>>>(
        (const _Float16*)d_ws, pnum, pM);
    merge_kernel<<<NGROUP, 128, 0, stream>>>(pnum, pM, ob, out);
}